// Round 4
// baseline (56.335 us; speedup 1.0000x reference)
//
#include <hip/hip_runtime.h>
#include <hip/hip_bf16.h>

// GATLayer with scalar attention => uniform 1/deg over DISTINCT neighbors.
//   out[n, h*D+d] = sum_k W[h,d,k] * agg_x[n,k]
//   agg_x[n,:]    = mean_{j in distinct nbr(n)} x[j,:]  (mean over all N if deg==0)
// agg + W cast to bf16, final GEMM via MFMA. 4 launches total.

constexpr int NN = 4096;          // nodes
constexpr int DD = 256;           // channels
constexpr int HH = 8;             // heads
constexpr int EE = 131072;        // edges
constexpr int MW = NN / 32;       // 128 mask words per row
constexpr int NOUT = HH * DD;     // 2048
constexpr int ZERO_F4 = (NN * MW * 4 + DD * 4) / 16;   // mask + colsum, float4 units

typedef __attribute__((ext_vector_type(4))) float f32x4;
typedef __attribute__((ext_vector_type(8))) short s16x8;

__device__ inline short f2bf(float f) {
    __hip_bfloat16 h = __float2bfloat16(f);
    return *reinterpret_cast<short*>(&h);
}

// ---- stage 1 (fused): zero mask+colsum via float4 stores; convert W to bf16 ----
__global__ __launch_bounds__(256) void prep_k(const float* __restrict__ w,
                                              short* __restrict__ wb,
                                              float4* __restrict__ zbase) {
    int b = blockIdx.x;
    int t = threadIdx.x;
    if (b < 513) {                       // zero 2 MB mask + 1 KB colsum
        int idx = b * 256 + t;
        if (idx < ZERO_F4) zbase[idx] = make_float4(0.f, 0.f, 0.f, 0.f);
    } else {                             // W fp32 -> bf16, one float4 per thread
        int i = (b - 513) * 256 + t;     // 0 .. 131071
        float4 v = reinterpret_cast<const float4*>(w)[i];
        short4 o;
        o.x = f2bf(v.x); o.y = f2bf(v.y); o.z = f2bf(v.z); o.w = f2bf(v.w);
        reinterpret_cast<short4*>(wb)[i] = o;
    }
}

// ---- stage 2 (fused): edge scatter into bitmask; colsum of x (deg==0 fallback) ----
__global__ __launch_bounds__(256) void edges_colsum_k(
        const int* __restrict__ ei, int stride, unsigned int* __restrict__ mask,
        const float* __restrict__ x, float* __restrict__ colsum) {
    int b = blockIdx.x;
    int t = threadIdx.x;
    if (b < 512) {                       // 512*256 = 131072 edges
        int e = b * 256 + t;
        int u = ei[(size_t)e * stride];              // src (row of adj)
        int v = ei[((size_t)EE + e) * stride];       // dst (col of adj)
        atomicOr(&mask[(size_t)u * MW + (v >> 5)], 1u << (v & 31));
    } else {                             // 64 blocks x 64 rows
        int r0 = (b - 512) * 64;
        float acc = 0.f;
        for (int r = 0; r < 64; ++r) acc += x[(size_t)(r0 + r) * DD + t];
        atomicAdd(&colsum[t], acc);
    }
}

// ---- stage 3: neighbor mean. Compact bitmask -> LDS list, then 4-deep loads ----
__global__ __launch_bounds__(256) void aggregate_k(
        const float* __restrict__ x, const unsigned int* __restrict__ mask,
        const float* __restrict__ colsum, short* __restrict__ aggb) {
    int i = blockIdx.x;
    int t = threadIdx.x;
    int slot = t >> 6;            // wave id 0..3
    int c4 = (t & 63) << 2;       // 4 channels per lane -> 64 lanes = full row

    __shared__ int nbr[NN];       // worst-case 4096 neighbors (16 KB)
    __shared__ int cnt;
    __shared__ float part[4][DD];

    if (t == 0) cnt = 0;
    __syncthreads();
    if (t < MW) {                 // compact bits -> index list (LDS atomics)
        unsigned int m = mask[(size_t)i * MW + t];
        while (m) {
            int b = __ffs(m) - 1;
            m &= m - 1;
            nbr[atomicAdd(&cnt, 1)] = t * 32 + b;
        }
    }
    __syncthreads();
    int deg = cnt;

    // each wave consumes chunks of 4 rows: 4 independent loads in flight
    float4 acc = make_float4(0.f, 0.f, 0.f, 0.f);
    for (int r0 = slot * 4; r0 < deg; r0 += 16) {
        int nn[4];
        float4 v[4];
#pragma unroll
        for (int j = 0; j < 4; ++j)
            nn[j] = (r0 + j < deg) ? nbr[r0 + j] : nbr[r0];
#pragma unroll
        for (int j = 0; j < 4; ++j)
            v[j] = *reinterpret_cast<const float4*>(&x[(size_t)nn[j] * DD + c4]);
#pragma unroll
        for (int j = 0; j < 4; ++j)
            if (r0 + j < deg) {
                acc.x += v[j].x; acc.y += v[j].y; acc.z += v[j].z; acc.w += v[j].w;
            }
    }
    *reinterpret_cast<float4*>(&part[slot][c4]) = acc;
    __syncthreads();

    float s = part[0][t] + part[1][t] + part[2][t] + part[3][t];
    float res = (deg > 0) ? s * (1.f / (float)deg)
                          : colsum[t] * (1.f / (float)NN);
    aggb[(size_t)i * DD + t] = f2bf(res);
}

// ------- stage 4: MFMA GEMM  C[4096][2048] = A[4096][256] * B[2048][256]^T -------
// bf16 in, fp32 out. 128x64 block tile, 4 waves (2x2), 64x32 per wave.
// K=256 => 8 steps of 32, 2-deep register double-buffer. 1024 blocks = 4/CU.
__global__ __launch_bounds__(256, 4) void gemm_mfma_k(
        const short* __restrict__ A, const short* __restrict__ B,
        float* __restrict__ C) {
    int tid = threadIdx.x;
    int lane = tid & 63;
    int w = tid >> 6;
    int wr = w >> 1, wc = w & 1;
    int m0 = blockIdx.y * 128 + wr * 64;
    int n0 = blockIdx.x * 64 + wc * 32;
    int lr = lane & 15;                  // row (A) / col (B) within fragment
    int lk = (lane >> 4) * 8;            // k sub-block within 32-step

    f32x4 acc[4][2] = {};
    s16x8 a[2][4], b[2][2];

#define LOADF(buf, kbase)                                                  \
    {                                                                      \
        _Pragma("unroll")                                                  \
        for (int i = 0; i < 4; ++i)                                        \
            a[buf][i] = *reinterpret_cast<const s16x8*>(                   \
                &A[(size_t)(m0 + i * 16 + lr) * DD + (kbase) + lk]);       \
        _Pragma("unroll")                                                  \
        for (int j = 0; j < 2; ++j)                                        \
            b[buf][j] = *reinterpret_cast<const s16x8*>(                   \
                &B[(size_t)(n0 + j * 16 + lr) * DD + (kbase) + lk]);       \
    }

    LOADF(0, 0)
#pragma unroll
    for (int kk = 0; kk < 8; ++kk) {
        int cur = kk & 1;
        if (kk < 7) LOADF(cur ^ 1, (kk + 1) * 32)
#pragma unroll
        for (int i = 0; i < 4; ++i)
#pragma unroll
            for (int j = 0; j < 2; ++j)
                acc[i][j] = __builtin_amdgcn_mfma_f32_16x16x32_bf16(
                    a[cur][i], b[cur][j], acc[i][j], 0, 0, 0);
    }
#undef LOADF

    // C/D layout: col = lane&15, row = (lane>>4)*4 + reg
    int crow = (lane >> 4) * 4;
    int ccol = lane & 15;
#pragma unroll
    for (int i = 0; i < 4; ++i)
#pragma unroll
        for (int j = 0; j < 2; ++j)
#pragma unroll
            for (int r = 0; r < 4; ++r)
                C[(size_t)(m0 + i * 16 + crow + r) * NOUT + n0 + j * 16 + ccol]
                    = acc[i][j][r];
}

extern "C" void kernel_launch(void* const* d_in, const int* in_sizes, int n_in,
                              void* d_out, int out_size, void* d_ws, size_t ws_size,
                              hipStream_t stream) {
    const float* x  = (const float*)d_in[0];
    const float* lw = (const float*)d_in[1];   // [H][D][D] == [2048][256] row-major
    const int*   ei = (const int*)d_in[4];
    float* out = (float*)d_out;

    char* ws = (char*)d_ws;
    unsigned int* mask   = (unsigned int*)ws;                             // 2 MB
    float*        colsum = (float*)(ws + (size_t)NN * MW * 4);            // 1 KB
    short*        aggb   = (short*)(ws + (size_t)NN * MW * 4 + 1024);     // 2 MB bf16
    short*        lwb    = (short*)(ws + (size_t)NN * MW * 4 + 1024
                                       + (size_t)NN * DD * 2);            // 1 MB bf16

    // int64 edge_index delivered as int32 (2E elements) vs raw int64 (low words)
    int stride = (in_sizes[4] == 2 * EE) ? 1 : 2;

    prep_k<<<513 + 512, 256, 0, stream>>>(lw, lwb, (float4*)ws);
    edges_colsum_k<<<512 + 64, 256, 0, stream>>>(ei, stride, mask, x, colsum);
    aggregate_k<<<NN, 256, 0, stream>>>(x, mask, colsum, aggb);

    dim3 ggrid(NOUT / 64, NN / 128);   // (32, 32)
    gemm_mfma_k<<<ggrid, 256, 0, stream>>>(aggb, lwb, out);
}